// Round 4
// baseline (620.635 us; speedup 1.0000x reference)
//
#include <hip/hip_runtime.h>
#include <math.h>

#define B_  2
#define S_  2048
#define D_  1024
#define H_  16
#define DK_ 64

typedef float f32x4 __attribute__((ext_vector_type(4)));
typedef short short8 __attribute__((ext_vector_type(8)));
typedef unsigned short u16;

static __device__ __forceinline__ u16 f2bf(float x) {
    union { float f; unsigned u; } v; v.f = x;
    unsigned r = v.u + 0x7fffu + ((v.u >> 16) & 1u);
    return (u16)(r >> 16);
}

static __device__ __forceinline__ void gload_lds16(const void* g, void* l) {
    __builtin_amdgcn_global_load_lds((const __attribute__((address_space(1))) void*)g,
                                     (__attribute__((address_space(3))) void*)l,
                                     16, 0, 0);
}

#define MFMA16(a, b, c) __builtin_amdgcn_mfma_f32_16x16x32_bf16((a), (b), (c), 0, 0, 0)

// ---------------------------------------------------------------------------
// Fused prep: z=0..3 -> transpose+cast one 1024x1024 weight; z=4 -> cast hs.
// ---------------------------------------------------------------------------
__global__ __launch_bounds__(256) void prep(const float* __restrict__ hs,
                                            const float* __restrict__ w0,
                                            const float* __restrict__ w1,
                                            const float* __restrict__ w2,
                                            const float* __restrict__ w3,
                                            u16* __restrict__ hsb,
                                            u16* __restrict__ o0,
                                            u16* __restrict__ o1,
                                            u16* __restrict__ o2,
                                            u16* __restrict__ o3) {
    if (blockIdx.z == 4) {
        size_t i = ((size_t)(blockIdx.y * 32 + blockIdx.x) * 256 + threadIdx.x) * 16;
#pragma unroll
        for (int c = 0; c < 2; ++c) {
            float4 a = *(const float4*)(hs + i + c * 8);
            float4 b = *(const float4*)(hs + i + c * 8 + 4);
            short8 o;
            o[0] = (short)f2bf(a.x); o[1] = (short)f2bf(a.y);
            o[2] = (short)f2bf(a.z); o[3] = (short)f2bf(a.w);
            o[4] = (short)f2bf(b.x); o[5] = (short)f2bf(b.y);
            o[6] = (short)f2bf(b.z); o[7] = (short)f2bf(b.w);
            *(short8*)(hsb + i + c * 8) = o;
        }
        return;
    }
    __shared__ float t[32][33];
    const float* W; u16* O;
    switch (blockIdx.z) {
        case 0: W = w0; O = o0; break;
        case 1: W = w1; O = o1; break;
        case 2: W = w2; O = o2; break;
        default: W = w3; O = o3; break;
    }
    const int K = 1024, N = 1024;
    int tx = threadIdx.x & 31, ty = threadIdx.x >> 5;
    int n0 = blockIdx.x * 32, k0 = blockIdx.y * 32;
#pragma unroll
    for (int r = ty; r < 32; r += 8)
        t[r][tx] = W[(size_t)(k0 + r) * N + n0 + tx];
    __syncthreads();
#pragma unroll
    for (int r = ty; r < 32; r += 8)
        O[(size_t)(n0 + r) * K + k0 + tx] = f2bf(t[tx][r]);
}

// ---------------------------------------------------------------------------
// bf16 MFMA GEMM, 128x128 tile, BK=32, double-buffered LDS (unchanged, passed).
// MODE 0: fused QKV epilogue -> Qb, Kb, Vt[b][h][d][s].  MODE 2: fp32 out.
// ---------------------------------------------------------------------------
template <int MODE>
__global__ __launch_bounds__(256, 3) void gemm_bf16(const u16* __restrict__ A,
                                                    const u16* __restrict__ Bt,
                                                    void* __restrict__ C0,
                                                    u16* __restrict__ Kb,
                                                    u16* __restrict__ Vt,
                                                    int M, int N, int K) {
    __shared__ alignas(16) u16 As[2][128 * 32];
    __shared__ alignas(16) u16 Bs[2][128 * 32];

    const int tid  = threadIdx.x;
    const int wave = tid >> 6;
    const int lane = tid & 63;
    const int col  = lane & 15;
    const int quad = lane >> 4;
    const int bm   = blockIdx.y * 128;
    const int bn   = blockIdx.x * 128;
    const int wm   = (wave >> 1) * 64;
    const int wn   = (wave & 1) * 64;

    f32x4 acc[4][4];
#pragma unroll
    for (int i = 0; i < 4; ++i)
#pragma unroll
        for (int j = 0; j < 4; ++j) acc[i][j] = (f32x4){0.f, 0.f, 0.f, 0.f};

    const int srow = wave * 32 + (lane >> 2);
    const int ksel = (lane & 3) * 8;
    const u16* gA = A  + (size_t)(bm + srow) * K + ksel;
    const u16* gB = Bt + (size_t)(bn + srow) * K + ksel;
    const size_t rowJump = (size_t)16 * K;
    const int ldsOff = wave * 2048;

    auto stage = [&](int k0, int bi) {
        char* a = (char*)As[bi] + ldsOff;
        char* b = (char*)Bs[bi] + ldsOff;
        gload_lds16(gA + k0, a);
        gload_lds16(gA + k0 + rowJump, a + 1024);
        gload_lds16(gB + k0, b);
        gload_lds16(gB + k0 + rowJump, b + 1024);
    };

    stage(0, 0);
    const int NIT = K >> 5;
    for (int it = 0; it < NIT; ++it) {
        const int bi = it & 1;
        __syncthreads();                     // buf[bi] ready (staged one iter ago)
        if (it + 1 < NIT) stage((it + 1) * 32, bi ^ 1);

        const u16* as = As[bi];
        const u16* bs = Bs[bi];
        short8 af[4], bfr[4];
#pragma unroll
        for (int mi = 0; mi < 4; ++mi)
            af[mi] = *(const short8*)&as[(wm + mi * 16 + col) * 32 + quad * 8];
#pragma unroll
        for (int ni = 0; ni < 4; ++ni)
            bfr[ni] = *(const short8*)&bs[(wn + ni * 16 + col) * 32 + quad * 8];
#pragma unroll
        for (int mi = 0; mi < 4; ++mi)
#pragma unroll
            for (int ni = 0; ni < 4; ++ni)
                acc[mi][ni] = MFMA16(af[mi], bfr[ni], acc[mi][ni]);
    }

#pragma unroll
    for (int mi = 0; mi < 4; ++mi)
#pragma unroll
        for (int ni = 0; ni < 4; ++ni) {
            const int rowb = bm + wm + mi * 16 + quad * 4;
            const int coln = bn + wn + ni * 16 + col;
            f32x4 v = acc[mi][ni];
            if (MODE == 2) {
                float* O = (float*)C0;
#pragma unroll
                for (int r = 0; r < 4; ++r)
                    O[(size_t)(rowb + r) * N + coln] = v[r];
            } else {
                if (coln < D_) {
                    u16* Qb = (u16*)C0;
#pragma unroll
                    for (int r = 0; r < 4; ++r)
                        Qb[(size_t)(rowb + r) * D_ + coln] = f2bf(v[r]);
                } else if (coln < 2 * D_) {
#pragma unroll
                    for (int r = 0; r < 4; ++r)
                        Kb[(size_t)(rowb + r) * D_ + (coln - D_)] = f2bf(v[r]);
                } else {
                    const int nn = coln - 2 * D_;
                    const int hh = nn >> 6, d = nn & 63;
                    const int bb = rowb >> 11, sb = rowb & 2047;
                    ushort4 pk;
                    pk.x = f2bf(v[0]); pk.y = f2bf(v[1]);
                    pk.z = f2bf(v[2]); pk.w = f2bf(v[3]);
                    *(ushort4*)&Vt[(((size_t)bb * H_ + hh) * DK_ + d) * S_ + sb] = pk;
                }
            }
        }
}

// ---------------------------------------------------------------------------
// MFMA flash attention.  Numerics identical to the 522us baseline except:
//  - P->bf16 conversion via v_cvt_pk_bf16_f32 (same RNE rounding as f2bf;
//    differs only for denormal P < 1e-38, which cannot affect the output).
// Scheduling changes (bit-exact):
//  - all per-r softmax elementwise ops vectorized as f32x4 -> v_pk_*_f32
//  - s_setprio(1) around MFMA clusters (T5)
//  - register-double-buffered bias prefetch (kept from round 3)
// ---------------------------------------------------------------------------
#define ATTN_BODY(it_, CUR, NXT)                                               \
  {                                                                            \
    const int j0 = (it_) * 64;                                                 \
    const int bi = (it_) & 1;                                                  \
    __syncthreads();                                                           \
    if ((it_) < 31) {                                                          \
      stage(j0 + 64, bi ^ 1);                                                  \
      _Pragma("unroll")                                                        \
      for (int ng = 0; ng < 4; ++ng)                                           \
        _Pragma("unroll")                                                      \
        for (int r = 0; r < 4; ++r)                                            \
          NXT[ng * 4 + r] =                                                    \
              bias_base[(size_t)r * S_ + j0 + 64 + ng * 16 + col];             \
    }                                                                          \
    const char* bK = smem + bi * 16384;                                        \
    const char* bV = bK + 8192;                                                \
    f32x4 sc[4];                                                               \
    __builtin_amdgcn_s_setprio(1);                                             \
    _Pragma("unroll")                                                          \
    for (int ng = 0; ng < 4; ++ng) {                                           \
      const char* rp = bK + (ng * 16 + col) * 128;                             \
      short8 k0 = *(const short8*)(rp + sl0);                                  \
      short8 k1 = *(const short8*)(rp + sl1);                                  \
      f32x4 z = (f32x4){0.f, 0.f, 0.f, 0.f};                                   \
      z = MFMA16(aq0, k0, z);                                                  \
      z = MFMA16(aq1, k1, z);                                                  \
      sc[ng] = z;                                                              \
    }                                                                          \
    __builtin_amdgcn_s_setprio(0);                                             \
    _Pragma("unroll")                                                          \
    for (int ng = 0; ng < 4; ++ng) {                                           \
      f32x4 bb4 = {CUR[ng * 4 + 0], CUR[ng * 4 + 1],                           \
                   CUR[ng * 4 + 2], CUR[ng * 4 + 3]};                          \
      sc[ng] += bb4;                                                           \
    }                                                                          \
    f32x4 rm4 = __builtin_elementwise_max(                                     \
        __builtin_elementwise_max(sc[0], sc[1]),                               \
        __builtin_elementwise_max(sc[2], sc[3]));                              \
    _Pragma("unroll")                                                          \
    for (int r = 0; r < 4; ++r) {                                              \
      float rm = rm4[r];                                                       \
      rm = fmaxf(rm, __shfl_xor(rm, 1));                                       \
      rm = fmaxf(rm, __shfl_xor(rm, 2));                                       \
      rm = fmaxf(rm, __shfl_xor(rm, 4));                                       \
      rm = fmaxf(rm, __shfl_xor(rm, 8));                                       \
      rm4[r] = rm;                                                             \
    }                                                                          \
    f32x4 mn4 = __builtin_elementwise_max(mst4, rm4);                          \
    f32x4 al4;                                                                 \
    _Pragma("unroll")                                                          \
    for (int r = 0; r < 4; ++r) al4[r] = __expf(mst4[r] - mn4[r]);             \
    mst4 = mn4;                                                                \
    f32x4 rs4 = (f32x4){0.f, 0.f, 0.f, 0.f};                                   \
    _Pragma("unroll")                                                          \
    for (int ng = 0; ng < 4; ++ng) {                                           \
      f32x4 t = sc[ng] - mst4;                                                 \
      _Pragma("unroll")                                                        \
      for (int r = 0; r < 4; ++r) t[r] = __expf(t[r]);                         \
      sc[ng] = t;                                                              \
      rs4 += t;                                                                \
    }                                                                          \
    _Pragma("unroll")                                                          \
    for (int r = 0; r < 4; ++r) {                                              \
      float s = rs4[r];                                                        \
      s += __shfl_xor(s, 1);                                                   \
      s += __shfl_xor(s, 2);                                                   \
      s += __shfl_xor(s, 4);                                                   \
      s += __shfl_xor(s, 8);                                                   \
      rs4[r] = s;                                                              \
    }                                                                          \
    lst4 = lst4 * al4 + rs4;                                                   \
    _Pragma("unroll")                                                          \
    for (int ndg = 0; ndg < 4; ++ndg) o[ndg] *= al4;                           \
    _Pragma("unroll")                                                          \
    for (int ng = 0; ng < 4; ++ng) {                                           \
      const int cb = ng * 2 + (col >> 3);                                      \
      unsigned pk01, pk23;                                                     \
      asm("v_cvt_pk_bf16_f32 %0, %1, %2"                                       \
          : "=v"(pk01) : "v"(sc[ng][0]), "v"(sc[ng][1]));                      \
      asm("v_cvt_pk_bf16_f32 %0, %1, %2"                                       \
          : "=v"(pk23) : "v"(sc[ng][2]), "v"(sc[ng][3]));                      \
      const int qb_ = quad * 4;                                                \
      *(u16*)(pw + (qb_ + 0) * 128 + ((cb ^ ((qb_ + 0) & 7)) * 16) + cx * 2) = \
          (u16)pk01;                                                           \
      *(u16*)(pw + (qb_ + 1) * 128 + ((cb ^ ((qb_ + 1) & 7)) * 16) + cx * 2) = \
          (u16)(pk01 >> 16);                                                   \
      *(u16*)(pw + (qb_ + 2) * 128 + ((cb ^ ((qb_ + 2) & 7)) * 16) + cx * 2) = \
          (u16)pk23;                                                           \
      *(u16*)(pw + (qb_ + 3) * 128 + ((cb ^ ((qb_ + 3) & 7)) * 16) + cx * 2) = \
          (u16)(pk23 >> 16);                                                   \
    }                                                                          \
    short8 ap0 = *(const short8*)(pw + col * 128 + sl0);                       \
    short8 ap1 = *(const short8*)(pw + col * 128 + sl1);                       \
    __builtin_amdgcn_s_setprio(1);                                             \
    _Pragma("unroll")                                                          \
    for (int ndg = 0; ndg < 4; ++ndg) {                                        \
      const char* rp = bV + (ndg * 16 + col) * 128;                            \
      short8 v0 = *(const short8*)(rp + sl0);                                  \
      short8 v1 = *(const short8*)(rp + sl1);                                  \
      o[ndg] = MFMA16(ap0, v0, o[ndg]);                                        \
      o[ndg] = MFMA16(ap1, v1, o[ndg]);                                        \
    }                                                                          \
    __builtin_amdgcn_s_setprio(0);                                             \
  }

__global__ __launch_bounds__(256, 4) void attn_mfma(const u16* __restrict__ Qb,
                                                    const u16* __restrict__ Kb,
                                                    const u16* __restrict__ Vt,
                                                    const float* __restrict__ bias,
                                                    u16* __restrict__ Ctx) {
    __shared__ alignas(16) char smem[40960];  // K0 V0 K1 V1 (8KB each) + Ps 8KB

    const int tid  = threadIdx.x;
    const int wave = tid >> 6;
    const int lane = tid & 63;
    const int col  = lane & 15;
    const int quad = lane >> 4;
    const int cx   = col & 7;
    const int sl0  = (quad ^ cx) * 16;
    const int sl1  = ((4 + quad) ^ cx) * 16;

    const int gid = blockIdx.x;
    const int qt  = gid & 31;
    const int h   = (gid >> 5) & 15;
    const int b   = gid >> 9;
    const int q0  = qt * 64 + wave * 16;

    short8 aq0, aq1;
    {
        const u16* qp = Qb + (size_t)(b * S_ + q0 + col) * D_ + h * 64 + quad * 8;
        aq0 = *(const short8*)qp;
        aq1 = *(const short8*)(qp + 32);
    }

    const int c0 = tid, c1 = tid + 256;
    const int r0 = c0 >> 3, g0 = (c0 & 7) ^ (r0 & 7);
    const int r1 = c1 >> 3, g1 = (c1 & 7) ^ (r1 & 7);
    const u16* kT = Kb + (size_t)b * S_ * D_ + h * 64;
    const u16* vT = Vt + ((size_t)b * H_ + h) * (size_t)64 * S_;
    const size_t kOff0 = (size_t)r0 * D_ + g0 * 8;
    const size_t kOff1 = (size_t)r1 * D_ + g1 * 8;
    const size_t vOff0 = (size_t)r0 * S_ + g0 * 8;
    const size_t vOff1 = (size_t)r1 * S_ + g1 * 8;

    auto stage = [&](int j0s, int bis) {
        char* base = smem + bis * 16384;
        gload_lds16(kT + (size_t)j0s * D_ + kOff0, base + wave * 1024);
        gload_lds16(kT + (size_t)j0s * D_ + kOff1, base + 4096 + wave * 1024);
        gload_lds16(vT + j0s + vOff0, base + 8192 + wave * 1024);
        gload_lds16(vT + j0s + vOff1, base + 12288 + wave * 1024);
    };

    f32x4 o[4];
#pragma unroll
    for (int i = 0; i < 4; ++i) o[i] = (f32x4){0.f, 0.f, 0.f, 0.f};
    f32x4 mst4 = (f32x4){-INFINITY, -INFINITY, -INFINITY, -INFINITY};
    f32x4 lst4 = (f32x4){0.f, 0.f, 0.f, 0.f};

    const float* bias_base = bias + ((size_t)h * S_ + (q0 + quad * 4)) * S_;
    char* pw = smem + 32768 + wave * 2048;

    // Prime bias registers for it=0 (in flight while K/V tile 0 stages).
    float bbA[16], bbB[16];
#pragma unroll
    for (int ng = 0; ng < 4; ++ng)
#pragma unroll
        for (int r = 0; r < 4; ++r)
            bbA[ng * 4 + r] = bias_base[(size_t)r * S_ + ng * 16 + col];

    stage(0, 0);

#pragma unroll 1
    for (int itp = 0; itp < 16; ++itp) {
        ATTN_BODY(2 * itp,     bbA, bbB)
        ATTN_BODY(2 * itp + 1, bbB, bbA)
    }

    f32x4 inv4;
#pragma unroll
    for (int r = 0; r < 4; ++r) inv4[r] = 1.f / lst4[r];
#pragma unroll
    for (int ndg = 0; ndg < 4; ++ndg)
#pragma unroll
        for (int r = 0; r < 4; ++r)
            Ctx[(size_t)(b * S_ + q0 + quad * 4 + r) * D_ + h * 64 + ndg * 16 + col] =
                f2bf(o[ndg][r] * inv4[r]);
}

// ---------------------------------------------------------------------------
// Launch
// ---------------------------------------------------------------------------
extern "C" void kernel_launch(void* const* d_in, const int* in_sizes, int n_in,
                              void* d_out, int out_size, void* d_ws, size_t ws_size,
                              hipStream_t stream) {
    const float* hs   = (const float*)d_in[0];
    const float* bias = (const float*)d_in[1];
    const float* wq   = (const float*)d_in[3];
    const float* wk   = (const float*)d_in[4];
    const float* wv   = (const float*)d_in[5];
    const float* wo   = (const float*)d_in[6];
    float* out = (float*)d_out;

    char* ws = (char*)d_ws;
    u16* hs_bf = (u16*)ws;
    u16* qb    = (u16*)(ws + 8 * 1024 * 1024);
    u16* kb    = (u16*)(ws + 16 * 1024 * 1024);
    u16* vt    = (u16*)(ws + 24 * 1024 * 1024);
    u16* cb    = (u16*)(ws + 32 * 1024 * 1024);
    u16* wqt   = (u16*)(ws + 40 * 1024 * 1024);  // wqt/wkt/wvt contiguous
    u16* wkt   = (u16*)(ws + 42 * 1024 * 1024);
    u16* wvt   = (u16*)(ws + 44 * 1024 * 1024);
    u16* wot   = (u16*)(ws + 46 * 1024 * 1024);

    const int M = B_ * S_;

    prep<<<dim3(32, 32, 5), 256, 0, stream>>>(hs, wq, wk, wv, wo,
                                              hs_bf, wqt, wkt, wvt, wot);

    gemm_bf16<0><<<dim3(3 * D_ / 128, M / 128), 256, 0, stream>>>(
        hs_bf, wqt, (void*)qb, kb, vt, M, 3 * D_, D_);

    attn_mfma<<<B_ * H_ * (S_ / 64), 256, 0, stream>>>(qb, kb, vt, bias, cb);

    gemm_bf16<2><<<dim3(D_ / 128, M / 128), 256, 0, stream>>>(
        cb, wot, (void*)out, nullptr, nullptr, M, D_, D_);
}

// Round 5
// 513.888 us; speedup vs baseline: 1.2077x; 1.2077x over previous
//
#include <hip/hip_runtime.h>
#include <math.h>

#define B_  2
#define S_  2048
#define D_  1024
#define H_  16
#define DK_ 64

typedef float f32x4 __attribute__((ext_vector_type(4)));
typedef short short8 __attribute__((ext_vector_type(8)));
typedef unsigned short u16;

static __device__ __forceinline__ u16 f2bf(float x) {
    union { float f; unsigned u; } v; v.f = x;
    unsigned r = v.u + 0x7fffu + ((v.u >> 16) & 1u);
    return (u16)(r >> 16);
}

static __device__ __forceinline__ void gload_lds16(const void* g, void* l) {
    __builtin_amdgcn_global_load_lds((const __attribute__((address_space(1))) void*)g,
                                     (__attribute__((address_space(3))) void*)l,
                                     16, 0, 0);
}

#define MFMA16(a, b, c) __builtin_amdgcn_mfma_f32_16x16x32_bf16((a), (b), (c), 0, 0, 0)

// ---------------------------------------------------------------------------
// Fused prep: z=0..3 -> transpose+cast one 1024x1024 weight; z=4 -> cast hs.
// ---------------------------------------------------------------------------
__global__ __launch_bounds__(256) void prep(const float* __restrict__ hs,
                                            const float* __restrict__ w0,
                                            const float* __restrict__ w1,
                                            const float* __restrict__ w2,
                                            const float* __restrict__ w3,
                                            u16* __restrict__ hsb,
                                            u16* __restrict__ o0,
                                            u16* __restrict__ o1,
                                            u16* __restrict__ o2,
                                            u16* __restrict__ o3) {
    if (blockIdx.z == 4) {
        size_t i = ((size_t)(blockIdx.y * 32 + blockIdx.x) * 256 + threadIdx.x) * 16;
#pragma unroll
        for (int c = 0; c < 2; ++c) {
            float4 a = *(const float4*)(hs + i + c * 8);
            float4 b = *(const float4*)(hs + i + c * 8 + 4);
            short8 o;
            o[0] = (short)f2bf(a.x); o[1] = (short)f2bf(a.y);
            o[2] = (short)f2bf(a.z); o[3] = (short)f2bf(a.w);
            o[4] = (short)f2bf(b.x); o[5] = (short)f2bf(b.y);
            o[6] = (short)f2bf(b.z); o[7] = (short)f2bf(b.w);
            *(short8*)(hsb + i + c * 8) = o;
        }
        return;
    }
    __shared__ float t[32][33];
    const float* W; u16* O;
    switch (blockIdx.z) {
        case 0: W = w0; O = o0; break;
        case 1: W = w1; O = o1; break;
        case 2: W = w2; O = o2; break;
        default: W = w3; O = o3; break;
    }
    const int K = 1024, N = 1024;
    int tx = threadIdx.x & 31, ty = threadIdx.x >> 5;
    int n0 = blockIdx.x * 32, k0 = blockIdx.y * 32;
#pragma unroll
    for (int r = ty; r < 32; r += 8)
        t[r][tx] = W[(size_t)(k0 + r) * N + n0 + tx];
    __syncthreads();
#pragma unroll
    for (int r = ty; r < 32; r += 8)
        O[(size_t)(n0 + r) * K + k0 + tx] = f2bf(t[tx][r]);
}

// ---------------------------------------------------------------------------
// bf16 MFMA GEMM, 128x128 tile, BK=32, double-buffered LDS (unchanged).
// MODE 0: fused QKV epilogue -> Qb, Kb, Vt[b][h][d][s].  MODE 2: fp32 out.
// ---------------------------------------------------------------------------
template <int MODE>
__global__ __launch_bounds__(256, 3) void gemm_bf16(const u16* __restrict__ A,
                                                    const u16* __restrict__ Bt,
                                                    void* __restrict__ C0,
                                                    u16* __restrict__ Kb,
                                                    u16* __restrict__ Vt,
                                                    int M, int N, int K) {
    __shared__ alignas(16) u16 As[2][128 * 32];
    __shared__ alignas(16) u16 Bs[2][128 * 32];

    const int tid  = threadIdx.x;
    const int wave = tid >> 6;
    const int lane = tid & 63;
    const int col  = lane & 15;
    const int quad = lane >> 4;
    const int bm   = blockIdx.y * 128;
    const int bn   = blockIdx.x * 128;
    const int wm   = (wave >> 1) * 64;
    const int wn   = (wave & 1) * 64;

    f32x4 acc[4][4];
#pragma unroll
    for (int i = 0; i < 4; ++i)
#pragma unroll
        for (int j = 0; j < 4; ++j) acc[i][j] = (f32x4){0.f, 0.f, 0.f, 0.f};

    const int srow = wave * 32 + (lane >> 2);
    const int ksel = (lane & 3) * 8;
    const u16* gA = A  + (size_t)(bm + srow) * K + ksel;
    const u16* gB = Bt + (size_t)(bn + srow) * K + ksel;
    const size_t rowJump = (size_t)16 * K;
    const int ldsOff = wave * 2048;

    auto stage = [&](int k0, int bi) {
        char* a = (char*)As[bi] + ldsOff;
        char* b = (char*)Bs[bi] + ldsOff;
        gload_lds16(gA + k0, a);
        gload_lds16(gA + k0 + rowJump, a + 1024);
        gload_lds16(gB + k0, b);
        gload_lds16(gB + k0 + rowJump, b + 1024);
    };

    stage(0, 0);
    const int NIT = K >> 5;
    for (int it = 0; it < NIT; ++it) {
        const int bi = it & 1;
        __syncthreads();                     // buf[bi] ready (staged one iter ago)
        if (it + 1 < NIT) stage((it + 1) * 32, bi ^ 1);

        const u16* as = As[bi];
        const u16* bs = Bs[bi];
        short8 af[4], bfr[4];
#pragma unroll
        for (int mi = 0; mi < 4; ++mi)
            af[mi] = *(const short8*)&as[(wm + mi * 16 + col) * 32 + quad * 8];
#pragma unroll
        for (int ni = 0; ni < 4; ++ni)
            bfr[ni] = *(const short8*)&bs[(wn + ni * 16 + col) * 32 + quad * 8];
#pragma unroll
        for (int mi = 0; mi < 4; ++mi)
#pragma unroll
            for (int ni = 0; ni < 4; ++ni)
                acc[mi][ni] = MFMA16(af[mi], bfr[ni], acc[mi][ni]);
    }

#pragma unroll
    for (int mi = 0; mi < 4; ++mi)
#pragma unroll
        for (int ni = 0; ni < 4; ++ni) {
            const int rowb = bm + wm + mi * 16 + quad * 4;
            const int coln = bn + wn + ni * 16 + col;
            f32x4 v = acc[mi][ni];
            if (MODE == 2) {
                float* O = (float*)C0;
#pragma unroll
                for (int r = 0; r < 4; ++r)
                    O[(size_t)(rowb + r) * N + coln] = v[r];
            } else {
                if (coln < D_) {
                    u16* Qb = (u16*)C0;
#pragma unroll
                    for (int r = 0; r < 4; ++r)
                        Qb[(size_t)(rowb + r) * D_ + coln] = f2bf(v[r]);
                } else if (coln < 2 * D_) {
#pragma unroll
                    for (int r = 0; r < 4; ++r)
                        Kb[(size_t)(rowb + r) * D_ + (coln - D_)] = f2bf(v[r]);
                } else {
                    const int nn = coln - 2 * D_;
                    const int hh = nn >> 6, d = nn & 63;
                    const int bb = rowb >> 11, sb = rowb & 2047;
                    ushort4 pk;
                    pk.x = f2bf(v[0]); pk.y = f2bf(v[1]);
                    pk.z = f2bf(v[2]); pk.w = f2bf(v[3]);
                    *(ushort4*)&Vt[(((size_t)bb * H_ + hh) * DK_ + d) * S_ + sb] = pk;
                }
            }
        }
}

// ---------------------------------------------------------------------------
// MFMA flash attention — round-3 body (bit-exact 522us numerics: scalar
// softmax, __expf, f2bf P-write, no setprio, bias reg double-buffer).
// SINGLE change this round: grid decode b=gid&1 (was gid>>9) so the b=0/b=1
// twin blocks of the same (h,qt) run adjacently and share bias tiles in
// L2/L3 instead of fetching the 256MB bias from HBM once per batch.
// ---------------------------------------------------------------------------
#define ATTN_BODY(it_, CUR, NXT)                                               \
  {                                                                            \
    const int j0 = (it_) * 64;                                                 \
    const int bi = (it_) & 1;                                                  \
    __syncthreads();                                                           \
    if ((it_) < 31) {                                                          \
      stage(j0 + 64, bi ^ 1);                                                  \
      _Pragma("unroll")                                                        \
      for (int ng = 0; ng < 4; ++ng)                                           \
        _Pragma("unroll")                                                      \
        for (int r = 0; r < 4; ++r)                                            \
          NXT[ng * 4 + r] =                                                    \
              bias_base[(size_t)r * S_ + j0 + 64 + ng * 16 + col];             \
    }                                                                          \
    const char* bK = smem + bi * 16384;                                        \
    const char* bV = bK + 8192;                                                \
    f32x4 sc[4];                                                               \
    _Pragma("unroll")                                                          \
    for (int ng = 0; ng < 4; ++ng) {                                           \
      const char* rp = bK + (ng * 16 + col) * 128;                             \
      short8 k0 = *(const short8*)(rp + sl0);                                  \
      short8 k1 = *(const short8*)(rp + sl1);                                  \
      f32x4 z = (f32x4){0.f, 0.f, 0.f, 0.f};                                   \
      z = MFMA16(aq0, k0, z);                                                  \
      z = MFMA16(aq1, k1, z);                                                  \
      sc[ng] = z;                                                              \
    }                                                                          \
    _Pragma("unroll")                                                          \
    for (int ng = 0; ng < 4; ++ng)                                             \
      _Pragma("unroll")                                                        \
      for (int r = 0; r < 4; ++r) sc[ng][r] += CUR[ng * 4 + r];                \
    float alpha[4], rs[4];                                                     \
    _Pragma("unroll")                                                          \
    for (int r = 0; r < 4; ++r) {                                              \
      float rm = fmaxf(fmaxf(sc[0][r], sc[1][r]), fmaxf(sc[2][r], sc[3][r])); \
      rm = fmaxf(rm, __shfl_xor(rm, 1));                                       \
      rm = fmaxf(rm, __shfl_xor(rm, 2));                                       \
      rm = fmaxf(rm, __shfl_xor(rm, 4));                                       \
      rm = fmaxf(rm, __shfl_xor(rm, 8));                                       \
      float mn = fmaxf(mst[r], rm);                                            \
      alpha[r] = __expf(mst[r] - mn);                                          \
      mst[r] = mn;                                                             \
      rs[r] = 0.f;                                                             \
    }                                                                          \
    _Pragma("unroll")                                                          \
    for (int ng = 0; ng < 4; ++ng)                                             \
      _Pragma("unroll")                                                        \
      for (int r = 0; r < 4; ++r) {                                            \
        float p = __expf(sc[ng][r] - mst[r]);                                  \
        sc[ng][r] = p;                                                         \
        rs[r] += p;                                                            \
      }                                                                        \
    _Pragma("unroll")                                                          \
    for (int r = 0; r < 4; ++r) {                                              \
      float s = rs[r];                                                         \
      s += __shfl_xor(s, 1);                                                   \
      s += __shfl_xor(s, 2);                                                   \
      s += __shfl_xor(s, 4);                                                   \
      s += __shfl_xor(s, 8);                                                   \
      lst[r] = lst[r] * alpha[r] + s;                                          \
    }                                                                          \
    _Pragma("unroll")                                                          \
    for (int ndg = 0; ndg < 4; ++ndg)                                          \
      _Pragma("unroll")                                                        \
      for (int r = 0; r < 4; ++r) o[ndg][r] *= alpha[r];                       \
    _Pragma("unroll")                                                          \
    for (int ng = 0; ng < 4; ++ng) {                                           \
      const int cb = ng * 2 + (col >> 3);                                      \
      _Pragma("unroll")                                                        \
      for (int r = 0; r < 4; ++r) {                                            \
        const int q = quad * 4 + r;                                            \
        *(u16*)(pw + q * 128 + ((cb ^ (q & 7)) * 16) + cx * 2) =               \
            f2bf(sc[ng][r]);                                                   \
      }                                                                        \
    }                                                                          \
    short8 ap0 = *(const short8*)(pw + col * 128 + sl0);                       \
    short8 ap1 = *(const short8*)(pw + col * 128 + sl1);                       \
    _Pragma("unroll")                                                          \
    for (int ndg = 0; ndg < 4; ++ndg) {                                        \
      const char* rp = bV + (ndg * 16 + col) * 128;                            \
      short8 v0 = *(const short8*)(rp + sl0);                                  \
      short8 v1 = *(const short8*)(rp + sl1);                                  \
      o[ndg] = MFMA16(ap0, v0, o[ndg]);                                        \
      o[ndg] = MFMA16(ap1, v1, o[ndg]);                                        \
    }                                                                          \
  }

__global__ __launch_bounds__(256, 4) void attn_mfma(const u16* __restrict__ Qb,
                                                    const u16* __restrict__ Kb,
                                                    const u16* __restrict__ Vt,
                                                    const float* __restrict__ bias,
                                                    u16* __restrict__ Ctx) {
    __shared__ alignas(16) char smem[40960];  // K0 V0 K1 V1 (8KB each) + Ps 8KB

    const int tid  = threadIdx.x;
    const int wave = tid >> 6;
    const int lane = tid & 63;
    const int col  = lane & 15;
    const int quad = lane >> 4;
    const int cx   = col & 7;
    const int sl0  = (quad ^ cx) * 16;
    const int sl1  = ((4 + quad) ^ cx) * 16;

    // Grid decode: batch in the LOW bit so b=0/b=1 twins of the same (h,qt)
    // are adjacent blocks -> the 256MB bias is fetched once, twin hits L2/L3.
    const int gid = blockIdx.x;
    const int b   = gid & 1;
    const int qt  = (gid >> 1) & 31;
    const int h   = gid >> 6;
    const int q0  = qt * 64 + wave * 16;

    short8 aq0, aq1;
    {
        const u16* qp = Qb + (size_t)(b * S_ + q0 + col) * D_ + h * 64 + quad * 8;
        aq0 = *(const short8*)qp;
        aq1 = *(const short8*)(qp + 32);
    }

    const int c0 = tid, c1 = tid + 256;
    const int r0 = c0 >> 3, g0 = (c0 & 7) ^ (r0 & 7);
    const int r1 = c1 >> 3, g1 = (c1 & 7) ^ (r1 & 7);
    const u16* kT = Kb + (size_t)b * S_ * D_ + h * 64;
    const u16* vT = Vt + ((size_t)b * H_ + h) * (size_t)64 * S_;
    const size_t kOff0 = (size_t)r0 * D_ + g0 * 8;
    const size_t kOff1 = (size_t)r1 * D_ + g1 * 8;
    const size_t vOff0 = (size_t)r0 * S_ + g0 * 8;
    const size_t vOff1 = (size_t)r1 * S_ + g1 * 8;

    auto stage = [&](int j0s, int bis) {
        char* base = smem + bis * 16384;
        gload_lds16(kT + (size_t)j0s * D_ + kOff0, base + wave * 1024);
        gload_lds16(kT + (size_t)j0s * D_ + kOff1, base + 4096 + wave * 1024);
        gload_lds16(vT + j0s + vOff0, base + 8192 + wave * 1024);
        gload_lds16(vT + j0s + vOff1, base + 12288 + wave * 1024);
    };

    f32x4 o[4];
#pragma unroll
    for (int i = 0; i < 4; ++i) o[i] = (f32x4){0.f, 0.f, 0.f, 0.f};
    float mst[4], lst[4];
#pragma unroll
    for (int r = 0; r < 4; ++r) { mst[r] = -INFINITY; lst[r] = 0.f; }

    const float* bias_base = bias + ((size_t)h * S_ + (q0 + quad * 4)) * S_;
    char* pw = smem + 32768 + wave * 2048;

    // Prime bias registers for it=0 (in flight while K/V tile 0 stages).
    float bbA[16], bbB[16];
#pragma unroll
    for (int ng = 0; ng < 4; ++ng)
#pragma unroll
        for (int r = 0; r < 4; ++r)
            bbA[ng * 4 + r] = bias_base[(size_t)r * S_ + ng * 16 + col];

    stage(0, 0);

#pragma unroll 1
    for (int itp = 0; itp < 16; ++itp) {
        ATTN_BODY(2 * itp,     bbA, bbB)
        ATTN_BODY(2 * itp + 1, bbB, bbA)
    }

    float inv[4];
#pragma unroll
    for (int r = 0; r < 4; ++r) inv[r] = 1.f / lst[r];
#pragma unroll
    for (int ndg = 0; ndg < 4; ++ndg)
#pragma unroll
        for (int r = 0; r < 4; ++r)
            Ctx[(size_t)(b * S_ + q0 + quad * 4 + r) * D_ + h * 64 + ndg * 16 + col] =
                f2bf(o[ndg][r] * inv[r]);
}

// ---------------------------------------------------------------------------
// Launch
// ---------------------------------------------------------------------------
extern "C" void kernel_launch(void* const* d_in, const int* in_sizes, int n_in,
                              void* d_out, int out_size, void* d_ws, size_t ws_size,
                              hipStream_t stream) {
    const float* hs   = (const float*)d_in[0];
    const float* bias = (const float*)d_in[1];
    const float* wq   = (const float*)d_in[3];
    const float* wk   = (const float*)d_in[4];
    const float* wv   = (const float*)d_in[5];
    const float* wo   = (const float*)d_in[6];
    float* out = (float*)d_out;

    char* ws = (char*)d_ws;
    u16* hs_bf = (u16*)ws;
    u16* qb    = (u16*)(ws + 8 * 1024 * 1024);
    u16* kb    = (u16*)(ws + 16 * 1024 * 1024);
    u16* vt    = (u16*)(ws + 24 * 1024 * 1024);
    u16* cb    = (u16*)(ws + 32 * 1024 * 1024);
    u16* wqt   = (u16*)(ws + 40 * 1024 * 1024);  // wqt/wkt/wvt contiguous
    u16* wkt   = (u16*)(ws + 42 * 1024 * 1024);
    u16* wvt   = (u16*)(ws + 44 * 1024 * 1024);
    u16* wot   = (u16*)(ws + 46 * 1024 * 1024);

    const int M = B_ * S_;

    prep<<<dim3(32, 32, 5), 256, 0, stream>>>(hs, wq, wk, wv, wo,
                                              hs_bf, wqt, wkt, wvt, wot);

    gemm_bf16<0><<<dim3(3 * D_ / 128, M / 128), 256, 0, stream>>>(
        hs_bf, wqt, (void*)qb, kb, vt, M, 3 * D_, D_);

    attn_mfma<<<B_ * H_ * (S_ / 64), 256, 0, stream>>>(qb, kb, vt, bias, cb);

    gemm_bf16<2><<<dim3(D_ / 128, M / 128), 256, 0, stream>>>(
        cb, wot, (void*)out, nullptr, nullptr, M, D_, D_);
}